// Round 3
// baseline (176.831 us; speedup 1.0000x reference)
//
#include <hip/hip_runtime.h>
#include <math.h>

// Monotone cubic spline flow. B*D = 2,097,152 elements, K = 8 bins.
// R5: software-pipelined grid-stride loop. R2 (E=1), R3 (E=4 ILP), R4
// (dense loads + swizzled LDS) ALL land at ~61-65us with every pipe idle
// (VALU<=25%, HBM 20%, LDS ~0). Little's-law post-mortem: each wave issues
// its loads, then sits in ONE giant s_waitcnt for ~16k cycles -> the
// exposed memory round-trip per 64 elements is the limiter, and co-resident
// waves can't hide it because they're all in the same wait.
// Fix: each thread handles 8 elements (grid-stride), double-buffered in
// registers: issue iteration i+1's 7 global loads BEFORE computing
// iteration i. Steady-state exposes the round trip once per 512 elements;
// compute (~800 issue-cycles/iter/wave) hides the rest. vmcnt queue order
// guarantees waiting on iter-i's loads never drains iter-i+1's.
// Keeps R2/R3's verified algebra (no-max softmax, positive slopes =>
// sign terms == 2, fused monotone-predicate bin search). No LDS.

constexpr int K = 8;
constexpr int ITERS = 8;                 // elements per thread
constexpr float TAIL = 3.0f;
constexpr float MIN_BIN = 0.001f;

__device__ __forceinline__ float rcpf(float v) {
    return __builtin_amdgcn_rcpf(v);     // v_rcp_f32, ~1 ulp
}

struct Elem {
    float4 wa, wb, ha, hb;               // 8 widths + 8 heights
    float x, dl, dr;
};

__device__ __forceinline__ Elem load_elem(
    const float* __restrict__ x_, const float* __restrict__ w_,
    const float* __restrict__ h_, const float* __restrict__ dl_,
    const float* __restrict__ dr_, int i)
{
    Elem e;
    const float4* w4 = (const float4*)w_ + 2 * (size_t)i;
    const float4* h4 = (const float4*)h_ + 2 * (size_t)i;
    e.wa = w4[0]; e.wb = w4[1];
    e.ha = h4[0]; e.hb = h4[1];
    e.x  = x_[i];
    e.dl = dl_[i];
    e.dr = dr_[i];
    return e;
}

__device__ __forceinline__ void process(
    const Elem& el, float* __restrict__ out, float* __restrict__ lad, int i)
{
    float wr[K] = {el.wa.x, el.wa.y, el.wa.z, el.wa.w,
                   el.wb.x, el.wb.y, el.wb.z, el.wb.w};
    float hr[K] = {el.ha.x, el.ha.y, el.ha.z, el.ha.w,
                   el.hb.x, el.hb.y, el.hb.z, el.hb.w};

    // softmax + min-bin affine (no max-subtraction; inputs ~N(0,1))
    float sw = 0.0f, sh = 0.0f;
    #pragma unroll
    for (int k = 0; k < K; k++) { wr[k] = __expf(wr[k]); sw += wr[k]; }
    #pragma unroll
    for (int k = 0; k < K; k++) { hr[k] = __expf(hr[k]); sh += hr[k]; }
    float cwf = (1.0f - MIN_BIN * K) * rcpf(sw);
    float chf = (1.0f - MIN_BIN * K) * rcpf(sh);
    #pragma unroll
    for (int k = 0; k < K; k++) {
        wr[k] = fmaf(wr[k], cwf, MIN_BIN);
        hr[k] = fmaf(hr[k], chf, MIN_BIN);
    }

    // cumulative knots + slopes (all strictly positive)
    float cw[K + 1], ch[K + 1], s[K];
    cw[0] = 0.0f; ch[0] = 0.0f;
    #pragma unroll
    for (int k = 0; k < K; k++) {
        cw[k + 1] = cw[k] + wr[k];
        ch[k + 1] = ch[k] + hr[k];
        s[k] = hr[k] * rcpf(wr[k]);
    }

    // derivatives: endpoints (sigmoid) + interior (monotone)
    float dv[K + 1];
    dv[0] = 3.0f * s[0]     * rcpf(1.0f + __expf(-el.dl));
    dv[K] = 3.0f * s[K - 1] * rcpf(1.0f + __expf(-el.dr));
    #pragma unroll
    for (int k = 0; k < K - 1; k++) {
        float num = wr[k + 1] * s[k] + wr[k] * s[k + 1];
        dv[k + 1] = fminf(2.0f * fminf(s[k], s[k + 1]),
                          num * rcpf(wr[k] + wr[k + 1]));
    }

    // normalized position
    float t = fminf(fmaxf((el.x + TAIL) * (1.0f / (2.0f * TAIL)), 0.0f), 1.0f);

    // fused bin-search + gather via monotone predicates
    float wk = wr[0], sk = s[0], d0 = dv[0], d1 = dv[1], lw = 0.0f, dd = 0.0f;
    #pragma unroll
    for (int k = 1; k < K; k++) {
        bool p = (t >= cw[k]);
        wk = p ? wr[k]     : wk;
        sk = p ? s[k]      : sk;
        d0 = p ? dv[k]     : d0;
        d1 = p ? dv[k + 1] : d1;
        lw = p ? cw[k]     : lw;
        dd = p ? ch[k]     : dd;
    }

    // cubic evaluation
    float iw = rcpf(wk);
    float ia = (d0 + d1 - 2.0f * sk) * iw * iw;
    float ib = (3.0f * sk - 2.0f * d0 - d1) * iw;
    float sx = t - lw;
    float out_s = ((ia * sx + ib) * sx + d0) * sx + dd;
    float der   = (3.0f * ia * sx + 2.0f * ib) * sx + d0;
    float lad_s = __logf(fabsf(der));    // + log(6) - log(6) == 0

    out_s = fminf(fmaxf(out_s, 0.0f), 1.0f) * (2.0f * TAIL) - TAIL;

    bool inside = (el.x >= -TAIL) && (el.x <= TAIL);
    out[i] = inside ? out_s : el.x;
    lad[i] = inside ? lad_s : 0.0f;
}

__global__ __launch_bounds__(256) void cbs_kernel(
    const float* __restrict__ x_,
    const float* __restrict__ w_,
    const float* __restrict__ h_,
    const float* __restrict__ dl_,
    const float* __restrict__ dr_,
    float* __restrict__ out,
    float* __restrict__ lad,
    int n)
{
    int stride = gridDim.x * blockDim.x;                 // elements per iter
    int i = blockIdx.x * blockDim.x + threadIdx.x;

    if (i >= n) return;
    Elem cur = load_elem(x_, w_, h_, dl_, dr_, i);       // prologue load

    #pragma unroll
    for (int it = 0; it < ITERS; ++it) {
        int inext = i + stride;
        Elem nxt;
        bool have_next = (it + 1 < ITERS) && (inext < n);
        if (have_next)
            nxt = load_elem(x_, w_, h_, dl_, dr_, inext); // issue BEFORE compute

        process(cur, out, lad, i);                        // waits only on cur

        cur = nxt;                                        // renamed away by unroll
        i = inext;
        if (!have_next) break;
    }
}

extern "C" void kernel_launch(void* const* d_in, const int* in_sizes, int n_in,
                              void* d_out, int out_size, void* d_ws, size_t ws_size,
                              hipStream_t stream) {
    const float* x  = (const float*)d_in[0];
    const float* w  = (const float*)d_in[1];
    const float* h  = (const float*)d_in[2];
    const float* dl = (const float*)d_in[3];
    const float* dr = (const float*)d_in[4];
    int n = in_sizes[0];                 // 8192*256 = 2,097,152
    float* out = (float*)d_out;          // outputs, then logabsdet, concatenated
    float* lad = out + n;

    const int threads = 256;
    const int per_block = threads * ITERS;               // 2048
    const int blocks = (n + per_block - 1) / per_block;  // 1024
    cbs_kernel<<<blocks, threads, 0, stream>>>(x, w, h, dl, dr, out, lad, n);
}